// Round 1
// baseline (113.371 us; speedup 1.0000x reference)
//
#include <hip/hip_runtime.h>
#include <hip/hip_bf16.h>

// Problem constants
#define B_   2
#define CH   32      // C
#define S_   1024    // H*W
#define DM   64      // D_MODEL
#define NH   4       // N_HEADS
#define DH   16      // D_HEAD
#define COUT 64

// ws layout (floats):
//   [0..3]       a[h]        = (qv . kv)|head_h / sqrt(DH)
//   [16..271]    ov[o*4+h]   = sum_{d in head h} o_w[o,d]*vv[d]
//   [512 ..]     w[n][h][s]  64*4*1024 floats
#define WS_A   0
#define WS_OV  16
#define WS_W   512

#if __has_builtin(__builtin_amdgcn_exp2f)
#define EXP2F(x) __builtin_amdgcn_exp2f(x)
#else
#define EXP2F(x) exp2f(x)
#endif

__global__ __launch_bounds__(64) void k_prep(const float* __restrict__ embed_w,
                                             const float* __restrict__ q_w,
                                             const float* __restrict__ k_w,
                                             const float* __restrict__ v_w,
                                             const float* __restrict__ o_w,
                                             float* __restrict__ ws) {
    __shared__ float qv[DM], kv[DM], vv[DM];
    int d = threadIdx.x;
    float sq = 0.f, sk = 0.f, sv = 0.f;
    #pragma unroll 8
    for (int e = 0; e < DM; e++) {
        float em = embed_w[e];
        sq = fmaf(q_w[d * DM + e], em, sq);
        sk = fmaf(k_w[d * DM + e], em, sk);
        sv = fmaf(v_w[d * DM + e], em, sv);
    }
    qv[d] = sq; kv[d] = sk; vv[d] = sv;
    __syncthreads();
    if (d < NH) {
        float a = 0.f;
        #pragma unroll
        for (int i = 0; i < DH; i++) a = fmaf(qv[d * DH + i], kv[d * DH + i], a);
        ws[WS_A + d] = a * 0.25f;   // 1/sqrt(16)
    }
    // ov[o][h] = sum_{d in head h} o_w[o,d] * vv[d]
    int o = d;
    #pragma unroll
    for (int h = 0; h < NH; h++) {
        float s = 0.f;
        #pragma unroll
        for (int i = 0; i < DH; i++)
            s = fmaf(o_w[o * DM + h * DH + i], vv[h * DH + i], s);
        ws[WS_OV + o * NH + h] = s;
    }
}

// One block per (n, s-chunk of 64). 256 threads: tid>>6 = h, tid&63 = s_local.
// Each thread computes w(n,h,s) = softmax-weighted mean of t[n,:] with logits c*t[j].
__global__ __launch_bounds__(256) void k_attn(const float* __restrict__ x,
                                              const float* __restrict__ ws,
                                              float* __restrict__ wout) {
    __shared__ float t[S_];
    __shared__ float red[256];
    const int n = blockIdx.x >> 4;
    const int chunk = blockIdx.x & 15;
    const int b = n >> 5, c = n & 31;
    const int tid = threadIdx.x;

    // t[s] = x[b, s>>5, s&31, c] = x[b*32768 + s*32 + c]
    const float* xp = x + b * (S_ * CH) + c;
    float lmax = -1e30f, lmin = 1e30f;
    #pragma unroll
    for (int i = tid; i < S_; i += 256) {
        float v = xp[i * CH];
        t[i] = v;
        lmax = fmaxf(lmax, v);
        lmin = fminf(lmin, v);
    }
    red[tid] = lmax; __syncthreads();
    for (int off = 128; off; off >>= 1) {
        if (tid < off) red[tid] = fmaxf(red[tid], red[tid + off]);
        __syncthreads();
    }
    const float tmax = red[0]; __syncthreads();
    red[tid] = lmin; __syncthreads();
    for (int off = 128; off; off >>= 1) {
        if (tid < off) red[tid] = fminf(red[tid], red[tid + off]);
        __syncthreads();
    }
    const float tmin = red[0]; __syncthreads();

    const int h = tid >> 6;
    const int s = chunk * 64 + (tid & 63);
    const float a = ws[WS_A + h];
    const float cc = t[s] * a;
    const float L2E = 1.44269504088896f;
    const float cc2 = cc * L2E;
    // exact max of logits: cc>=0 -> cc*tmax, else cc*tmin
    const float m2 = (cc >= 0.f ? cc * tmax : cc * tmin) * L2E;

    float n0 = 0.f, n1 = 0.f, n2 = 0.f, n3 = 0.f;
    float d0 = 0.f, d1 = 0.f, d2 = 0.f, d3 = 0.f;
    for (int j = 0; j < S_; j += 4) {
        float t0 = t[j + 0], t1 = t[j + 1], t2 = t[j + 2], t3 = t[j + 3];
        float e0 = EXP2F(fmaf(cc2, t0, -m2));
        float e1 = EXP2F(fmaf(cc2, t1, -m2));
        float e2 = EXP2F(fmaf(cc2, t2, -m2));
        float e3 = EXP2F(fmaf(cc2, t3, -m2));
        n0 = fmaf(e0, t0, n0); d0 += e0;
        n1 = fmaf(e1, t1, n1); d1 += e1;
        n2 = fmaf(e2, t2, n2); d2 += e2;
        n3 = fmaf(e3, t3, n3); d3 += e3;
    }
    const float num = (n0 + n1) + (n2 + n3);
    const float den = (d0 + d1) + (d2 + d3);
    wout[(n * NH + h) * S_ + s] = num / den;
}

// One block per (b, s). Phase 1: 128 threads reduce over c for each h.
// Phase 2: 64 threads compute out[b,s,o] = sum_h ov[o,h] * W2[h].
__global__ __launch_bounds__(128) void k_out(const float* __restrict__ ws,
                                             const float* __restrict__ merge_w,
                                             float* __restrict__ out) {
    __shared__ float W2[NH];
    const int bs = blockIdx.x;             // b*1024 + s
    const int b = bs >> 10, s = bs & 1023;
    const int tid = threadIdx.x;
    const float* warr = ws + WS_W;
    const int h = tid >> 5, c = tid & 31;
    float val = merge_w[c] * warr[((b * CH + c) * NH + h) * S_ + s];
    // reduce across the 32-lane c-group (xor masks < 32 stay in-group)
    #pragma unroll
    for (int off = 16; off; off >>= 1) val += __shfl_xor(val, off, 64);
    if (c == 0) W2[h] = val;
    __syncthreads();
    if (tid < COUT) {
        float r = 0.f;
        #pragma unroll
        for (int hh = 0; hh < NH; hh++)
            r = fmaf(ws[WS_OV + tid * NH + hh], W2[hh], r);
        out[bs * COUT + tid] = r;
    }
}

extern "C" void kernel_launch(void* const* d_in, const int* in_sizes, int n_in,
                              void* d_out, int out_size, void* d_ws, size_t ws_size,
                              hipStream_t stream) {
    const float* x       = (const float*)d_in[0];
    const float* embed_w = (const float*)d_in[1];
    const float* q_w     = (const float*)d_in[2];
    const float* k_w     = (const float*)d_in[3];
    const float* v_w     = (const float*)d_in[4];
    const float* o_w     = (const float*)d_in[5];
    const float* merge_w = (const float*)d_in[6];
    float* ws  = (float*)d_ws;
    float* out = (float*)d_out;

    k_prep<<<1, 64, 0, stream>>>(embed_w, q_w, k_w, v_w, o_w, ws);
    k_attn<<<B_ * CH * 16, 256, 0, stream>>>(x, ws, ws + WS_W);
    k_out<<<B_ * S_, 128, 0, stream>>>(ws, merge_w, out);
}